// Round 2
// baseline (44538.297 us; speedup 1.0000x reference)
//
#include <hip/hip_runtime.h>
#include <stdint.h>

#define B_  16
#define T_  1024
#define H_  1024
#define E_  512
#define V_  256
#define C_  256

typedef __bf16 bf16x8 __attribute__((ext_vector_type(8)));
typedef float  f32x4  __attribute__((ext_vector_type(4)));
typedef unsigned short u16;

__device__ __forceinline__ float bf2f(u16 u) {
  union { unsigned int i; float f; } v; v.i = ((unsigned int)u) << 16; return v.f;
}
__device__ __forceinline__ u16 f2bf(float f) {
  union { float f; unsigned int i; } v; v.f = f;
  unsigned int u = v.i;
  return (u16)((u + 0x7fffu + ((u >> 16) & 1u)) >> 16);  // RNE
}
__device__ __forceinline__ bf16x8 ld_bf8(const u16* p) {
  uint4 v = *(const uint4*)p;
  return __builtin_bit_cast(bf16x8, v);
}
__device__ __forceinline__ float sigm(float x) { return 1.f / (1.f + __expf(-x)); }

// ---- dtype probe: enc_bih0 is uniform(-1/32,1/32). As bf16, every ushort has
// exponent<=122. As f32 read as ushorts, low halves are random mantissa bits
// (~50% have "exponent">=124). flag=1 => inputs are float32.
__global__ void probe_k(const u16* __restrict__ s, int* __restrict__ flag) {
  if (blockIdx.x == 0 && threadIdx.x == 0) {
    int cnt = 0;
    for (int i = 0; i < 256; ++i) {
      int e = (s[i] >> 7) & 0xFF;
      if (e >= 124) ++cnt;
    }
    flag[0] = (cnt >= 16) ? 1 : 0;
  }
}

// ---- normalize one array into bf16 workspace (copy or f32->bf16) ----
__global__ void cvt_k(const void* __restrict__ src, u16* __restrict__ dst, int n,
                      const int* __restrict__ flagp) {
  int i = blockIdx.x * blockDim.x + threadIdx.x;
  if (i >= n) return;
  if (*flagp) dst[i] = f2bf(((const float*)src)[i]);
  else        dst[i] = ((const u16*)src)[i];
}

// Per-layer step params; pointers pre-resolved host-side (ring slots etc).
struct LayerP {
  const u16* Wih;   // (4096, I) row-major bf16 (normalized)
  const u16* Whh;   // (4096, 1024)
  const u16* bih;   // (4096,)
  const u16* bhh;   // (4096,)
  const u16* in;    // use_tok: emb table (V,I); else h slot (B,H)
  const u16* hprev; // h slot (B,H) or nullptr (h==0)
  float* c;         // (B,H) f32 cell state
  u16* hout;        // h slot (B,H)
  int I, use_tok, t, active;
};
struct StepArgs {
  LayerP l0, l1;
  const int* tok;
  // fused logits (decoder only), for t = lg_t
  const u16* lg_h;   // hdec1 slot (B,H)
  const u16* outW;   // (C,H) bf16
  const u16* outb;   // (C,)
  void* out;         // d_out (dtype per flag)
  const int* flag;
  int lg_t, lg_active;
};

// grid = 144 blocks x 64 thr. blocks [0,64): layer0 t=s; [64,128): layer1 t=s-1;
// [128,144): logits for t=s-2. mfma_f32_16x16x32_bf16, M=16=batch.
// A-frag: A[m=lane&15][k=quad*8+j]; B rows = W rows (NxK); D: m=quad*4+r, n=lane&15.
__global__ __launch_bounds__(64) void lstm_step(StepArgs A) {
  const int bid  = blockIdx.x;
  const int lane = threadIdx.x;
  const int l15  = lane & 15;
  const int quad = lane >> 4;
  const int ko   = quad * 8;

  if (bid >= 128) {
    // ---------- logits tile: out[b, c, t] for c in [nt*16, nt*16+16) ----------
    if (!A.lg_active) return;
    const int nt = bid - 128;
    const u16* arow = A.lg_h + l15 * H_;
    const u16* brow = A.outW + (size_t)(nt * 16 + l15) * H_;
    f32x4 acc = {0.f, 0.f, 0.f, 0.f};
    #pragma unroll 4
    for (int kk = 0; kk < H_; kk += 32) {
      acc = __builtin_amdgcn_mfma_f32_16x16x32_bf16(ld_bf8(arow + kk + ko),
                                                    ld_bf8(brow + kk + ko), acc, 0, 0, 0);
    }
    const int c  = nt * 16 + l15;
    const float bv = bf2f(A.outb[c]);
    const int f32out = *A.flag;
    #pragma unroll
    for (int r = 0; r < 4; ++r) {
      const int b = quad * 4 + r;
      const size_t idx = ((size_t)b * C_ + c) * T_ + A.lg_t;
      const float v = acc[r] + bv;
      if (f32out) ((float*)A.out)[idx] = v;
      else        ((u16*)A.out)[idx]   = f2bf(v);
    }
    return;
  }

  const LayerP P = (bid >= 64) ? A.l1 : A.l0;
  if (!P.active) return;
  const int wave = bid & 63;
  const int n    = (wave << 4) + l15;   // gate/h column in [0,1024)

  f32x4 acc0 = {0.f,0.f,0.f,0.f};
  f32x4 acc1 = {0.f,0.f,0.f,0.f};
  f32x4 acc2 = {0.f,0.f,0.f,0.f};
  f32x4 acc3 = {0.f,0.f,0.f,0.f};

  // ---- input projection Wih @ x_t (K = I) ----
  {
    const int K = P.I;
    const u16* arow;
    if (P.use_tok) {
      const int tok = A.tok[l15 * T_ + P.t];
      arow = P.in + (size_t)tok * K;
    } else {
      arow = P.in + l15 * H_;
    }
    const u16* b0 = P.Wih + (size_t)(0 * 1024 + n) * K;
    const u16* b1 = P.Wih + (size_t)(1 * 1024 + n) * K;
    const u16* b2 = P.Wih + (size_t)(2 * 1024 + n) * K;
    const u16* b3 = P.Wih + (size_t)(3 * 1024 + n) * K;
    #pragma unroll 4
    for (int kk = 0; kk < K; kk += 32) {
      bf16x8 a = ld_bf8(arow + kk + ko);
      acc0 = __builtin_amdgcn_mfma_f32_16x16x32_bf16(a, ld_bf8(b0 + kk + ko), acc0, 0, 0, 0);
      acc1 = __builtin_amdgcn_mfma_f32_16x16x32_bf16(a, ld_bf8(b1 + kk + ko), acc1, 0, 0, 0);
      acc2 = __builtin_amdgcn_mfma_f32_16x16x32_bf16(a, ld_bf8(b2 + kk + ko), acc2, 0, 0, 0);
      acc3 = __builtin_amdgcn_mfma_f32_16x16x32_bf16(a, ld_bf8(b3 + kk + ko), acc3, 0, 0, 0);
    }
  }

  // ---- recurrent Whh @ h_{t-1} (K = H); skipped when h==0 ----
  if (P.hprev != nullptr) {
    const u16* arow = P.hprev + l15 * H_;
    const u16* b0 = P.Whh + (size_t)(0 * 1024 + n) * H_;
    const u16* b1 = P.Whh + (size_t)(1 * 1024 + n) * H_;
    const u16* b2 = P.Whh + (size_t)(2 * 1024 + n) * H_;
    const u16* b3 = P.Whh + (size_t)(3 * 1024 + n) * H_;
    #pragma unroll 4
    for (int kk = 0; kk < H_; kk += 32) {
      bf16x8 a = ld_bf8(arow + kk + ko);
      acc0 = __builtin_amdgcn_mfma_f32_16x16x32_bf16(a, ld_bf8(b0 + kk + ko), acc0, 0, 0, 0);
      acc1 = __builtin_amdgcn_mfma_f32_16x16x32_bf16(a, ld_bf8(b1 + kk + ko), acc1, 0, 0, 0);
      acc2 = __builtin_amdgcn_mfma_f32_16x16x32_bf16(a, ld_bf8(b2 + kk + ko), acc2, 0, 0, 0);
      acc3 = __builtin_amdgcn_mfma_f32_16x16x32_bf16(a, ld_bf8(b3 + kk + ko), acc3, 0, 0, 0);
    }
  }

  // ---- LSTM pointwise: gate order i, f, g, o ----
  const float bi = bf2f(P.bih[n])        + bf2f(P.bhh[n]);
  const float bf = bf2f(P.bih[1024 + n]) + bf2f(P.bhh[1024 + n]);
  const float bg = bf2f(P.bih[2048 + n]) + bf2f(P.bhh[2048 + n]);
  const float bo = bf2f(P.bih[3072 + n]) + bf2f(P.bhh[3072 + n]);
  #pragma unroll
  for (int r = 0; r < 4; ++r) {
    const int b = quad * 4 + r;
    const float iv = sigm(acc0[r] + bi);
    const float fv = sigm(acc1[r] + bf);
    const float gv = tanhf(acc2[r] + bg);
    const float ov = sigm(acc3[r] + bo);
    const float cold = P.c[b * H_ + n];
    const float cn = fv * cold + iv * gv;
    P.c[b * H_ + n] = cn;
    P.hout[b * H_ + n] = f2bf(ov * tanhf(cn));
  }
}

extern "C" void kernel_launch(void* const* d_in, const int* in_sizes, int n_in,
                              void* d_out, int out_size, void* d_ws, size_t ws_size,
                              hipStream_t stream) {
  (void)in_sizes; (void)n_in; (void)out_size; (void)ws_size;

  const int* x = (const int*)d_in[0];

  // ---- workspace layout (~60.3 MiB) ----
  char* ws = (char*)d_ws;
  int* flag = (int*)ws;
  char* base = ws + 256;
  size_t ob = 0;
  const int Is[4] = {E_, H_, E_, H_};   // enc0, enc1, dec0, dec1
  u16* p_eemb = (u16*)(base + ob); ob += (size_t)V_ * E_ * 2;
  u16* p_demb = (u16*)(base + ob); ob += (size_t)V_ * E_ * 2;
  u16 *pWih[4], *pWhh[4], *pbih[4], *pbhh[4];
  for (int l = 0; l < 4; ++l) {
    pWih[l] = (u16*)(base + ob); ob += (size_t)4096 * Is[l] * 2;
    pWhh[l] = (u16*)(base + ob); ob += (size_t)4096 * H_ * 2;
    pbih[l] = (u16*)(base + ob); ob += 4096 * 2;
    pbhh[l] = (u16*)(base + ob); ob += 4096 * 2;
  }
  u16* p_outW = (u16*)(base + ob); ob += (size_t)C_ * H_ * 2;
  u16* p_outb = (u16*)(base + ob); ob += C_ * 2;
  ob = (ob + 255) & ~(size_t)255;
  float* c0 = (float*)(base + ob); ob += (size_t)B_ * H_ * 4;
  float* c1 = (float*)(base + ob); ob += (size_t)B_ * H_ * 4;
  u16* ring = (u16*)(base + ob);   // 8 slots of (B,H): henc0[2],henc1[2],hdec0[2],hdec1[2]
  const size_t SLOT = (size_t)B_ * H_;
  u16* henc0[2] = { ring + 0*SLOT, ring + 1*SLOT };
  u16* henc1[2] = { ring + 2*SLOT, ring + 3*SLOT };
  u16* hdec0[2] = { ring + 4*SLOT, ring + 5*SLOT };
  u16* hdec1[2] = { ring + 6*SLOT, ring + 7*SLOT };

  // ---- 1. dtype probe (enc_bih0 = d_in[5]) ----
  probe_k<<<1, 64, 0, stream>>>((const u16*)d_in[5], flag);

  // ---- 2. normalize all float arrays to bf16 in ws ----
  struct Job { const void* s; u16* d; int n; };
  Job jobs[20];
  int nj = 0;
  jobs[nj++] = { d_in[1], p_eemb, V_ * E_ };
  jobs[nj++] = { d_in[2], p_demb, V_ * E_ };
  for (int l = 0; l < 4; ++l) {
    jobs[nj++] = { d_in[3 + 4*l], pWih[l], 4096 * Is[l] };
    jobs[nj++] = { d_in[4 + 4*l], pWhh[l], 4096 * H_ };
    jobs[nj++] = { d_in[5 + 4*l], pbih[l], 4096 };
    jobs[nj++] = { d_in[6 + 4*l], pbhh[l], 4096 };
  }
  jobs[nj++] = { d_in[19], p_outW, C_ * H_ };
  jobs[nj++] = { d_in[20], p_outb, C_ };
  for (int j = 0; j < nj; ++j)
    cvt_k<<<(jobs[j].n + 255) / 256, 256, 0, stream>>>(jobs[j].s, jobs[j].d, jobs[j].n, flag);

  hipMemsetAsync(c0, 0, 2 * (size_t)B_ * H_ * sizeof(float), stream);

  const dim3 gs(144), bs(64);

  // ---- 3. encoder: supersteps s=0..1024 ----
  for (int s = 0; s <= T_; ++s) {
    StepArgs A{};
    A.tok = x; A.flag = flag; A.out = d_out; A.outW = p_outW; A.outb = p_outb;
    A.lg_active = 0; A.lg_h = ring; A.lg_t = 0;
    A.l0.Wih = pWih[0]; A.l0.Whh = pWhh[0]; A.l0.bih = pbih[0]; A.l0.bhh = pbhh[0];
    A.l0.in = p_eemb; A.l0.use_tok = 1; A.l0.I = E_; A.l0.t = s;
    A.l0.active = (s < T_);
    A.l0.hprev = (s == 0) ? nullptr : henc0[(s - 1) & 1];
    A.l0.hout  = henc0[s & 1];
    A.l0.c = c0;
    A.l1.Wih = pWih[1]; A.l1.Whh = pWhh[1]; A.l1.bih = pbih[1]; A.l1.bhh = pbhh[1];
    A.l1.in = henc0[(s - 1) & 1]; A.l1.use_tok = 0; A.l1.I = H_; A.l1.t = s - 1;
    A.l1.active = (s >= 1);
    A.l1.hprev = (s >= 2) ? henc1[s & 1] : nullptr;   // slot (s-2)&1 == s&1
    A.l1.hout  = henc1[(s - 1) & 1];
    A.l1.c = c1;
    lstm_step<<<gs, bs, 0, stream>>>(A);
  }

  // ---- 4. decoder: supersteps s=0..1025 (logits for t=s-2 fused) ----
  for (int s = 0; s <= T_ + 1; ++s) {
    StepArgs A{};
    A.tok = x; A.flag = flag; A.out = d_out; A.outW = p_outW; A.outb = p_outb;
    A.l0.Wih = pWih[2]; A.l0.Whh = pWhh[2]; A.l0.bih = pbih[2]; A.l0.bhh = pbhh[2];
    A.l0.in = p_demb; A.l0.use_tok = 1; A.l0.I = E_; A.l0.t = s;
    A.l0.active = (s < T_);
    A.l0.hprev = (s == 0) ? henc0[1] : hdec0[(s - 1) & 1];   // enc t=1023 -> slot 1
    A.l0.hout  = hdec0[s & 1];
    A.l0.c = c0;                                             // enc final c -> dec init c
    A.l1.Wih = pWih[3]; A.l1.Whh = pWhh[3]; A.l1.bih = pbih[3]; A.l1.bhh = pbhh[3];
    A.l1.in = hdec0[(s - 1) & 1]; A.l1.use_tok = 0; A.l1.I = H_; A.l1.t = s - 1;
    A.l1.active = (s >= 1 && s <= T_);
    A.l1.hprev = (s == 1) ? henc1[1] : hdec1[s & 1];         // slot (s-2)&1 == s&1
    A.l1.hout  = hdec1[(s - 1) & 1];
    A.l1.c = c1;
    A.lg_active = (s >= 2);
    A.lg_t = s - 2;
    A.lg_h = hdec1[s & 1];                                   // slot (s-2)&1 == s&1
    A.lg_active = A.lg_active ? 1 : 0;
    lstm_step<<<gs, bs, 0, stream>>>(A);
  }
}